// Round 10
// baseline (62.922 us; speedup 1.0000x reference)
//
#include <hip/hip_runtime.h>
#include <hip/hip_bf16.h>

// Quanv1D: out[i] = bias[i] + sum_d s_i(d) |(W' m_p)_d|^2
// R10 = R9 (fp16 2-term GEMM, frag-order A, fused prep, launch_bounds(256,2)
// -- NEVER (,4), that miscompiles) with M-tile 32 -> 64:
//   each B fragment now feeds 8 MFMAs (4 mt x hi/lo), per-patch L2 B-traffic
//   halved (524 MB -> 262 MB). Phase 1 = R9's code run twice (s=0,1);
//   phases 3/4/5 = R2's proven 64-patch maps with fp16.

#define TOTAL_PATCHES 65480
#define LOUT 8185
#define LBATCH 8192

typedef _Float16 f16x8 __attribute__((ext_vector_type(8)));
typedef float f32x4 __attribute__((ext_vector_type(4)));

static __device__ __forceinline__ unsigned short f2h_bits(float f) {
  union { _Float16 h; unsigned short u; } v;
  v.h = (_Float16)f;
  return v.u;
}

// ---------------- Kernel 1: fused W'-build (blocks 0..255) + angle tables ----
// W' layout: flat_short_idx = ((kc*32 + nt)*64 + lane)*8 + j
// k = kc*32 + (lane>>4)*8 + j (K index), n = nt*16 + (lane&15) (col).
__global__ __launch_bounds__(256) void prep_all(const float* __restrict__ x,
                                                const float* __restrict__ w,
                                                unsigned short* __restrict__ wf16,
                                                float* __restrict__ cs,
                                                float* __restrict__ sn) {
  if (blockIdx.x >= 256) {
    int e = (blockIdx.x - 256) * 256 + threadIdx.x;
    float t = tanhf(x[e]);
    float s, c;
    __sincosf(1.57079632679489662f * t, &s, &c);
    cs[e] = c;
    sn[e] = s;
    return;
  }
  __shared__ float re[256], im[256];
  const int k = blockIdx.x;
  const int t = threadIdx.x;
  re[t] = 0.f; im[t] = 0.f;
  __syncthreads();
  if (t == 0) re[k] = 1.f;
  __syncthreads();
  for (int l = 0; l < 2; ++l) {
    for (int wi = 0; wi < 8; ++wi) {
      float phi = w[(l * 8 + wi) * 3 + 0];
      float th  = w[(l * 8 + wi) * 3 + 1];
      float om  = w[(l * 8 + wi) * 3 + 2];
      float ch = cosf(0.5f * th), sh = sinf(0.5f * th);
      float aa = 0.5f * (phi + om), bb = 0.5f * (phi - om);
      float ca = cosf(aa), sa = sinf(aa), cb = cosf(bb), sb = sinf(bb);
      float m00r = ch * ca, m00i = -ch * sa;
      float m01r = -sh * cb, m01i = -sh * sb;
      float m10r = sh * cb,  m10i = -sh * sb;
      float m11r = ch * ca,  m11i = ch * sa;
      int pos = 7 - wi;
      int mask = 1 << pos;
      int lowm = mask - 1;
      if (t < 128) {
        int pp = t;
        int d0 = ((pp & ~lowm) << 1) | (pp & lowm);
        int d1 = d0 | mask;
        float a0r = re[d0], a0i = im[d0], a1r = re[d1], a1i = im[d1];
        re[d0] = m00r * a0r - m00i * a0i + m01r * a1r - m01i * a1i;
        im[d0] = m00r * a0i + m00i * a0r + m01r * a1i + m01i * a1r;
        re[d1] = m10r * a0r - m10i * a0i + m11r * a1r - m11i * a1i;
        im[d1] = m10r * a0i + m10i * a0r + m11r * a1i + m11i * a1r;
      }
      __syncthreads();
    }
    int r = (l % 7) + 1;
    for (int wi = 0; wi < 8; ++wi) {
      int c = wi, tg = (wi + r) & 7;
      int pc = 7 - c, pt = 7 - tg;
      int p1 = pc > pt ? pc : pt, p0 = pc < pt ? pc : pt;
      if (t < 64) {
        int lm0 = (1 << p0) - 1;
        int v2 = ((t & ~lm0) << 1) | (t & lm0);
        int lm1 = (1 << p1) - 1;
        int db = ((v2 & ~lm1) << 1) | (v2 & lm1);
        int d0 = db | (1 << pc);
        int d1 = d0 | (1 << pt);
        float tr = re[d0], ti = im[d0];
        re[d0] = re[d1]; im[d0] = im[d1];
        re[d1] = tr;     im[d1] = ti;
      }
      __syncthreads();
    }
  }
  int pop = __popc(k) & 3;
  for (int idx = t; idx < 512; idx += 256) {
    int n = idx;
    int d = n & 255;
    float vr = re[d], vi = im[d];
    float pr, qi;
    if (pop == 0)      { pr =  vr; qi =  vi; }
    else if (pop == 1) { pr =  vi; qi = -vr; }
    else if (pop == 2) { pr = -vr; qi = -vi; }
    else               { pr = -vi; qi =  vr; }
    float val = (n < 256) ? pr : qi;
    int off = (((k >> 5) * 32 + (n >> 4)) * 64 + ((k >> 3) & 3) * 16 + (n & 15)) * 8 + (k & 7);
    wf16[off] = f2h_bits(val);
  }
}

// ---------------- Kernel 2: m-gen + fp16 GEMM + epilogue (M=64) ----------
__global__ __launch_bounds__(256, 2) void quanv_main(
    const float* __restrict__ cs, const float* __restrict__ sn,
    const f16x8* __restrict__ wf, const float* __restrict__ bias,
    float* __restrict__ out) {
  __shared__ __align__(16) unsigned short R0[64 * 264];  // A-frag hi (32768B used) / probs hi [64][264]
  __shared__ __align__(16) unsigned short R1[64 * 264];  // A-frag lo / probs lo
  __shared__ float esm[512];
  const int tid = threadIdx.x;
  const int lane = tid & 63;
  const int wave = tid >> 6;
  const int pbase = blockIdx.x * 64;

  // --- phase 1: m-tile [64 x 256] hi/lo fp16, FRAGMENT order ---
  // Two passes of R9's map: s = sub-tile (32 patches each).
  // thread (pl=tid&31, q=tid>>5): patch pbase+s*32+pl, k-octant q (= kc).
#pragma unroll
  for (int s = 0; s < 2; ++s) {
    int pl = tid & 31, q = tid >> 5;
    int patch = pbase + s * 32 + pl;
    if (patch > TOTAL_PATCHES - 1) patch = TOTAL_PATCHES - 1;
    int b = patch / LOUT;
    int l = patch - b * LOUT;
    int base = b * LBATCH + l;
    float fc[8], fs[8];
#pragma unroll
    for (int wq = 0; wq < 8; ++wq) { fc[wq] = cs[base + wq]; fs[wq] = sn[base + wq]; }
    // k = q*32 + idx5; k bits 7..5 = q (wires 0..2); idx5 bit lev = wire 7-lev
    float arr[32];
    arr[0] = ((q & 4) ? fs[0] : fc[0]) * ((q & 2) ? fs[1] : fc[1]) * ((q & 1) ? fs[2] : fc[2]);
#pragma unroll
    for (int lev = 0; lev < 5; ++lev) {
      int wq = 7 - lev;
      int sz = 1 << lev;
#pragma unroll
      for (int j = 0; j < 32; ++j) {
        if (j < sz) {
          float a = arr[j];
          arr[sz + j] = a * fs[wq];
          arr[j] = a * fc[wq];
        }
      }
    }
    int mtg = s * 2 + (pl >> 4);                    // global m-tile 0..3
    int fragbase = (q * 4 + mtg) * 64 + (pl & 15);
#pragma unroll
    for (int khalf = 0; khalf < 4; ++khalf) {
      f16x8 vH, vL;
#pragma unroll
      for (int jj = 0; jj < 8; ++jj) {
        float a = arr[khalf * 8 + jj];
        _Float16 hh = (_Float16)a;
        vH[jj] = hh;
        vL[jj] = (_Float16)(a - (float)hh);
      }
      *(f16x8*)&R0[(fragbase + khalf * 16) * 8] = vH;
      *(f16x8*)&R1[(fragbase + khalf * 16) * 8] = vL;
    }
  }
  __syncthreads();

  // --- phase 2: fp16 GEMM: each B fragment feeds 8 MFMAs (4 mt x H/L) ---
  f32x4 acc[4][8];
#pragma unroll
  for (int i = 0; i < 4; ++i)
#pragma unroll
    for (int j = 0; j < 8; ++j) acc[i][j] = (f32x4){0.f, 0.f, 0.f, 0.f};

#pragma unroll
  for (int kc = 0; kc < 8; ++kc) {
    f16x8 afH[4], afL[4];
#pragma unroll
    for (int mt = 0; mt < 4; ++mt) {
      afH[mt] = *(const f16x8*)&R0[((kc * 4 + mt) * 64 + lane) * 8];
      afL[mt] = *(const f16x8*)&R1[((kc * 4 + mt) * 64 + lane) * 8];
    }
#pragma unroll
    for (int t8 = 0; t8 < 8; ++t8) {
      int nt = (t8 < 4) ? (wave * 4 + t8) : (16 + wave * 4 + t8 - 4);
      f16x8 b = wf[(kc * 32 + nt) * 64 + lane];
#pragma unroll
      for (int mt = 0; mt < 4; ++mt) {
        acc[mt][t8] = __builtin_amdgcn_mfma_f32_16x16x32_f16(afH[mt], b, acc[mt][t8], 0, 0, 0);
        acc[mt][t8] = __builtin_amdgcn_mfma_f32_16x16x32_f16(afL[mt], b, acc[mt][t8], 0, 0, 0);
      }
    }
  }

  __syncthreads();
  // --- phase 3: probs p = re^2+im^2, hi/lo fp16 -> [64][264] (alias) ---
#pragma unroll
  for (int mt = 0; mt < 4; ++mt)
#pragma unroll
    for (int t4 = 0; t4 < 4; ++t4)
#pragma unroll
      for (int r = 0; r < 4; ++r) {
        float vr = acc[mt][t4][r], vi = acc[mt][t4 + 4][r];
        float p = vr * vr + vi * vi;
        int patch_l = mt * 16 + (lane >> 4) * 4 + r;
        int d = (wave * 4 + t4) * 16 + (lane & 15);
        _Float16 hh = (_Float16)p;
        R0[patch_l * 264 + d] = f2h_bits(p);
        R1[patch_l * 264 + d] = f2h_bits(p - (float)hh);
      }
  __syncthreads();

  // --- phase 4: sign-GEMM (all 4 waves, 16 patches each) over hi+lo probs ---
  {
    f32x4 e4 = {0.f, 0.f, 0.f, 0.f};
    int io = lane & 15;
    int plr = wave * 16 + (lane & 15);
    int hi4 = lane >> 4;
#pragma unroll
    for (int kc2 = 0; kc2 < 8; ++kc2) {
      int k0 = kc2 * 32 + hi4 * 8;
      f16x8 aH = *(const f16x8*)&R0[plr * 264 + k0];
      f16x8 aL = *(const f16x8*)&R1[plr * 264 + k0];
      f16x8 b2;
#pragma unroll
      for (int bb = 0; bb < 8; ++bb) {
        _Float16 sv = (_Float16)0.f;
        if (io < 8) sv = (((k0 + bb) >> (7 - io)) & 1) ? (_Float16)(-1.f) : (_Float16)(1.f);
        b2[bb] = sv;
      }
      e4 = __builtin_amdgcn_mfma_f32_16x16x32_f16(aH, b2, e4, 0, 0, 0);
      e4 = __builtin_amdgcn_mfma_f32_16x16x32_f16(aL, b2, e4, 0, 0, 0);
    }
    if (io < 8) {
      float bv = bias[io];
#pragma unroll
      for (int r = 0; r < 4; ++r)
        esm[io * 64 + (wave * 16 + hi4 * 4 + r)] = e4[r] + bv;
    }
  }
  __syncthreads();

  // --- phase 5: coalesced transposed store out[b][i][l] ---
#pragma unroll
  for (int s = 0; s < 2; ++s) {
    int idx = tid + s * 256;
    int io2 = idx >> 6, pl2 = idx & 63;
    int patch = pbase + pl2;
    if (patch < TOTAL_PATCHES) {
      int b = patch / LOUT;
      int l = patch - b * LOUT;
      out[(b * 8 + io2) * LOUT + l] = esm[io2 * 64 + pl2];
    }
  }
}

extern "C" void kernel_launch(void* const* d_in, const int* in_sizes, int n_in,
                              void* d_out, int out_size, void* d_ws, size_t ws_size,
                              hipStream_t stream) {
  const float* x = (const float*)d_in[0];
  const float* w = (const float*)d_in[1];
  const float* bias = (const float*)d_in[2];
  float* out = (float*)d_out;
  char* ws = (char*)d_ws;
  unsigned short* wf16 = (unsigned short*)ws;           // 262144 B
  float* cs = (float*)(ws + 262144);                    // 262144 B
  float* sn = (float*)(ws + 524288);                    // 262144 B

  prep_all<<<512, 256, 0, stream>>>(x, w, wf16, cs, sn);
  quanv_main<<<1024, 256, 0, stream>>>(cs, sn, (const f16x8*)wf16, bias, out);
}

// Round 11
// 53.946 us; speedup vs baseline: 1.1664x; 1.1664x over previous
//
#include <hip/hip_runtime.h>
#include <hip/hip_bf16.h>

// Quanv1D: out[i] = bias[i] + sum_d s_i(d) |(W' m_p)_d|^2
// R11 = R10's M=64 tile with single-fp16 A (no hi/lo split) and single-fp16
// probs (no lo split). Error budget: A,B both fp16 => coherent worst
// delta-e ~2*2^-11*Sigma|phi| <= 0.016 < 0.0177 threshold, realistic ~1e-3
// (R8 proved the symmetric B-side rounding is invisible at the 2^-8 floor);
// probs single fp16 bounded by unitarity at 2^-12*Sigma p = 2.4e-4.
// LDS 35.8 KB => 4 blocks/CU (R9 occupancy) + R10 B-reuse (262 MB L2).
// launch_bounds(256,2) -- NEVER (,4), that miscompiles (R3/R4/R5).

#define TOTAL_PATCHES 65480
#define LOUT 8185
#define LBATCH 8192

typedef _Float16 f16x8 __attribute__((ext_vector_type(8)));
typedef float f32x4 __attribute__((ext_vector_type(4)));

static __device__ __forceinline__ unsigned short f2h_bits(float f) {
  union { _Float16 h; unsigned short u; } v;
  v.h = (_Float16)f;
  return v.u;
}

// ---------------- Kernel 1: fused W'-build (blocks 0..255) + angle tables ----
// W' layout: flat_short_idx = ((kc*32 + nt)*64 + lane)*8 + j
// k = kc*32 + (lane>>4)*8 + j (K index), n = nt*16 + (lane&15) (col).
__global__ __launch_bounds__(256) void prep_all(const float* __restrict__ x,
                                                const float* __restrict__ w,
                                                unsigned short* __restrict__ wf16,
                                                float* __restrict__ cs,
                                                float* __restrict__ sn) {
  if (blockIdx.x >= 256) {
    int e = (blockIdx.x - 256) * 256 + threadIdx.x;
    float t = tanhf(x[e]);
    float s, c;
    __sincosf(1.57079632679489662f * t, &s, &c);
    cs[e] = c;
    sn[e] = s;
    return;
  }
  __shared__ float re[256], im[256];
  const int k = blockIdx.x;
  const int t = threadIdx.x;
  re[t] = 0.f; im[t] = 0.f;
  __syncthreads();
  if (t == 0) re[k] = 1.f;
  __syncthreads();
  for (int l = 0; l < 2; ++l) {
    for (int wi = 0; wi < 8; ++wi) {
      float phi = w[(l * 8 + wi) * 3 + 0];
      float th  = w[(l * 8 + wi) * 3 + 1];
      float om  = w[(l * 8 + wi) * 3 + 2];
      float ch = cosf(0.5f * th), sh = sinf(0.5f * th);
      float aa = 0.5f * (phi + om), bb = 0.5f * (phi - om);
      float ca = cosf(aa), sa = sinf(aa), cb = cosf(bb), sb = sinf(bb);
      float m00r = ch * ca, m00i = -ch * sa;
      float m01r = -sh * cb, m01i = -sh * sb;
      float m10r = sh * cb,  m10i = -sh * sb;
      float m11r = ch * ca,  m11i = ch * sa;
      int pos = 7 - wi;
      int mask = 1 << pos;
      int lowm = mask - 1;
      if (t < 128) {
        int pp = t;
        int d0 = ((pp & ~lowm) << 1) | (pp & lowm);
        int d1 = d0 | mask;
        float a0r = re[d0], a0i = im[d0], a1r = re[d1], a1i = im[d1];
        re[d0] = m00r * a0r - m00i * a0i + m01r * a1r - m01i * a1i;
        im[d0] = m00r * a0i + m00i * a0r + m01r * a1i + m01i * a1r;
        re[d1] = m10r * a0r - m10i * a0i + m11r * a1r - m11i * a1i;
        im[d1] = m10r * a0i + m10i * a0r + m11r * a1i + m11i * a1r;
      }
      __syncthreads();
    }
    int r = (l % 7) + 1;
    for (int wi = 0; wi < 8; ++wi) {
      int c = wi, tg = (wi + r) & 7;
      int pc = 7 - c, pt = 7 - tg;
      int p1 = pc > pt ? pc : pt, p0 = pc < pt ? pc : pt;
      if (t < 64) {
        int lm0 = (1 << p0) - 1;
        int v2 = ((t & ~lm0) << 1) | (t & lm0);
        int lm1 = (1 << p1) - 1;
        int db = ((v2 & ~lm1) << 1) | (v2 & lm1);
        int d0 = db | (1 << pc);
        int d1 = d0 | (1 << pt);
        float tr = re[d0], ti = im[d0];
        re[d0] = re[d1]; im[d0] = im[d1];
        re[d1] = tr;     im[d1] = ti;
      }
      __syncthreads();
    }
  }
  int pop = __popc(k) & 3;
  for (int idx = t; idx < 512; idx += 256) {
    int n = idx;
    int d = n & 255;
    float vr = re[d], vi = im[d];
    float pr, qi;
    if (pop == 0)      { pr =  vr; qi =  vi; }
    else if (pop == 1) { pr =  vi; qi = -vr; }
    else if (pop == 2) { pr = -vr; qi = -vi; }
    else               { pr = -vi; qi =  vr; }
    float val = (n < 256) ? pr : qi;
    int off = (((k >> 5) * 32 + (n >> 4)) * 64 + ((k >> 3) & 3) * 16 + (n & 15)) * 8 + (k & 7);
    wf16[off] = f2h_bits(val);
  }
}

// ---------------- Kernel 2: m-gen + fp16 GEMM + epilogue (M=64, single A) ----
__global__ __launch_bounds__(256, 2) void quanv_main(
    const float* __restrict__ cs, const float* __restrict__ sn,
    const f16x8* __restrict__ wf, const float* __restrict__ bias,
    float* __restrict__ out) {
  __shared__ __align__(16) unsigned short R0[64 * 264];  // A-frag (32KB used) / probs [64][264]
  __shared__ float esm[512];
  const int tid = threadIdx.x;
  const int lane = tid & 63;
  const int wave = tid >> 6;
  const int pbase = blockIdx.x * 64;

  // --- phase 1: m-tile [64 x 256] fp16, FRAGMENT order (R10 map, hi only) ---
  // thread (pl=tid&31, q=tid>>5): patch pbase+s*32+pl, k-octant q (= kc).
#pragma unroll
  for (int s = 0; s < 2; ++s) {
    int pl = tid & 31, q = tid >> 5;
    int patch = pbase + s * 32 + pl;
    if (patch > TOTAL_PATCHES - 1) patch = TOTAL_PATCHES - 1;
    int b = patch / LOUT;
    int l = patch - b * LOUT;
    int base = b * LBATCH + l;
    float fc[8], fs[8];
#pragma unroll
    for (int wq = 0; wq < 8; ++wq) { fc[wq] = cs[base + wq]; fs[wq] = sn[base + wq]; }
    // k = q*32 + idx5; k bits 7..5 = q (wires 0..2); idx5 bit lev = wire 7-lev
    float arr[32];
    arr[0] = ((q & 4) ? fs[0] : fc[0]) * ((q & 2) ? fs[1] : fc[1]) * ((q & 1) ? fs[2] : fc[2]);
#pragma unroll
    for (int lev = 0; lev < 5; ++lev) {
      int wq = 7 - lev;
      int sz = 1 << lev;
#pragma unroll
      for (int j = 0; j < 32; ++j) {
        if (j < sz) {
          float a = arr[j];
          arr[sz + j] = a * fs[wq];
          arr[j] = a * fc[wq];
        }
      }
    }
    int mtg = s * 2 + (pl >> 4);                    // global m-tile 0..3
    int fragbase = (q * 4 + mtg) * 64 + (pl & 15);
#pragma unroll
    for (int khalf = 0; khalf < 4; ++khalf) {
      f16x8 vH;
#pragma unroll
      for (int jj = 0; jj < 8; ++jj) vH[jj] = (_Float16)arr[khalf * 8 + jj];
      *(f16x8*)&R0[(fragbase + khalf * 16) * 8] = vH;
    }
  }
  __syncthreads();

  // --- phase 2: fp16 GEMM: each B fragment feeds 4 MFMAs (4 mt) ---
  f32x4 acc[4][8];
#pragma unroll
  for (int i = 0; i < 4; ++i)
#pragma unroll
    for (int j = 0; j < 8; ++j) acc[i][j] = (f32x4){0.f, 0.f, 0.f, 0.f};

#pragma unroll
  for (int kc = 0; kc < 8; ++kc) {
    f16x8 afH[4];
#pragma unroll
    for (int mt = 0; mt < 4; ++mt)
      afH[mt] = *(const f16x8*)&R0[((kc * 4 + mt) * 64 + lane) * 8];
#pragma unroll
    for (int t8 = 0; t8 < 8; ++t8) {
      int nt = (t8 < 4) ? (wave * 4 + t8) : (16 + wave * 4 + t8 - 4);
      f16x8 b = wf[(kc * 32 + nt) * 64 + lane];
#pragma unroll
      for (int mt = 0; mt < 4; ++mt)
        acc[mt][t8] = __builtin_amdgcn_mfma_f32_16x16x32_f16(afH[mt], b, acc[mt][t8], 0, 0, 0);
    }
  }

  __syncthreads();
  // --- phase 3: probs p = re^2+im^2, single fp16 -> [64][264] (alias) ---
#pragma unroll
  for (int mt = 0; mt < 4; ++mt)
#pragma unroll
    for (int t4 = 0; t4 < 4; ++t4)
#pragma unroll
      for (int r = 0; r < 4; ++r) {
        float vr = acc[mt][t4][r], vi = acc[mt][t4 + 4][r];
        float p = vr * vr + vi * vi;
        int patch_l = mt * 16 + (lane >> 4) * 4 + r;
        int d = (wave * 4 + t4) * 16 + (lane & 15);
        R0[patch_l * 264 + d] = f2h_bits(p);
      }
  __syncthreads();

  // --- phase 4: sign-GEMM (all 4 waves, 16 patches each) ---
  {
    f32x4 e4 = {0.f, 0.f, 0.f, 0.f};
    int io = lane & 15;
    int plr = wave * 16 + (lane & 15);
    int hi4 = lane >> 4;
#pragma unroll
    for (int kc2 = 0; kc2 < 8; ++kc2) {
      int k0 = kc2 * 32 + hi4 * 8;
      f16x8 aH = *(const f16x8*)&R0[plr * 264 + k0];
      f16x8 b2;
#pragma unroll
      for (int bb = 0; bb < 8; ++bb) {
        _Float16 sv = (_Float16)0.f;
        if (io < 8) sv = (((k0 + bb) >> (7 - io)) & 1) ? (_Float16)(-1.f) : (_Float16)(1.f);
        b2[bb] = sv;
      }
      e4 = __builtin_amdgcn_mfma_f32_16x16x32_f16(aH, b2, e4, 0, 0, 0);
    }
    if (io < 8) {
      float bv = bias[io];
#pragma unroll
      for (int r = 0; r < 4; ++r)
        esm[io * 64 + (wave * 16 + hi4 * 4 + r)] = e4[r] + bv;
    }
  }
  __syncthreads();

  // --- phase 5: coalesced transposed store out[b][i][l] ---
#pragma unroll
  for (int s = 0; s < 2; ++s) {
    int idx = tid + s * 256;
    int io2 = idx >> 6, pl2 = idx & 63;
    int patch = pbase + pl2;
    if (patch < TOTAL_PATCHES) {
      int b = patch / LOUT;
      int l = patch - b * LOUT;
      out[(b * 8 + io2) * LOUT + l] = esm[io2 * 64 + pl2];
    }
  }
}

extern "C" void kernel_launch(void* const* d_in, const int* in_sizes, int n_in,
                              void* d_out, int out_size, void* d_ws, size_t ws_size,
                              hipStream_t stream) {
  const float* x = (const float*)d_in[0];
  const float* w = (const float*)d_in[1];
  const float* bias = (const float*)d_in[2];
  float* out = (float*)d_out;
  char* ws = (char*)d_ws;
  unsigned short* wf16 = (unsigned short*)ws;           // 262144 B
  float* cs = (float*)(ws + 262144);                    // 262144 B
  float* sn = (float*)(ws + 524288);                    // 262144 B

  prep_all<<<512, 256, 0, stream>>>(x, w, wf16, cs, sn);
  quanv_main<<<1024, 256, 0, stream>>>(cs, sn, (const f16x8*)wf16, bias, out);
}

// Round 12
// 39.037 us; speedup vs baseline: 1.6118x; 1.3819x over previous
//
#include <hip/hip_runtime.h>
#include <hip/hip_bf16.h>

// Quanv1D: out[i] = bias[i] + sum_d s_i(d) |(W' m_p)_d|^2
// R12 = R11 (fp16 single-term GEMM, M=64, frag-order A, fused prep) with the
// wave decomposition changed 4-wave/acc128 -> 8-wave/acc64:
//   CSV VGPR_Count excludes AGPRs; gfx950 unified file => R11 was ~256
//   unified regs/wave = 8 waves/CU. acc[4][4]=64 + ~40 arch ~= 104 unified
//   => 16 waves/CU. B traffic unchanged (each nt owned by one wave).
// launch_bounds(512,2) -- NEVER the 128-VGPR-cap variants ((256,4)-class),
// they silently miscompile acc-heavy MFMA kernels (R3/R4/R5 vs R7).

#define TOTAL_PATCHES 65480
#define LOUT 8185
#define LBATCH 8192

typedef _Float16 f16x8 __attribute__((ext_vector_type(8)));
typedef float f32x4 __attribute__((ext_vector_type(4)));

static __device__ __forceinline__ unsigned short f2h_bits(float f) {
  union { _Float16 h; unsigned short u; } v;
  v.h = (_Float16)f;
  return v.u;
}

// ---------------- Kernel 1: fused W'-build (blocks 0..255) + angle tables ----
// W' layout: flat_short_idx = ((kc*32 + nt)*64 + lane)*8 + j
// k = kc*32 + (lane>>4)*8 + j (K index), n = nt*16 + (lane&15) (col).
__global__ __launch_bounds__(256) void prep_all(const float* __restrict__ x,
                                                const float* __restrict__ w,
                                                unsigned short* __restrict__ wf16,
                                                float* __restrict__ cs,
                                                float* __restrict__ sn) {
  if (blockIdx.x >= 256) {
    int e = (blockIdx.x - 256) * 256 + threadIdx.x;
    float t = tanhf(x[e]);
    float s, c;
    __sincosf(1.57079632679489662f * t, &s, &c);
    cs[e] = c;
    sn[e] = s;
    return;
  }
  __shared__ float re[256], im[256];
  const int k = blockIdx.x;
  const int t = threadIdx.x;
  re[t] = 0.f; im[t] = 0.f;
  __syncthreads();
  if (t == 0) re[k] = 1.f;
  __syncthreads();
  for (int l = 0; l < 2; ++l) {
    for (int wi = 0; wi < 8; ++wi) {
      float phi = w[(l * 8 + wi) * 3 + 0];
      float th  = w[(l * 8 + wi) * 3 + 1];
      float om  = w[(l * 8 + wi) * 3 + 2];
      float ch = cosf(0.5f * th), sh = sinf(0.5f * th);
      float aa = 0.5f * (phi + om), bb = 0.5f * (phi - om);
      float ca = cosf(aa), sa = sinf(aa), cb = cosf(bb), sb = sinf(bb);
      float m00r = ch * ca, m00i = -ch * sa;
      float m01r = -sh * cb, m01i = -sh * sb;
      float m10r = sh * cb,  m10i = -sh * sb;
      float m11r = ch * ca,  m11i = ch * sa;
      int pos = 7 - wi;
      int mask = 1 << pos;
      int lowm = mask - 1;
      if (t < 128) {
        int pp = t;
        int d0 = ((pp & ~lowm) << 1) | (pp & lowm);
        int d1 = d0 | mask;
        float a0r = re[d0], a0i = im[d0], a1r = re[d1], a1i = im[d1];
        re[d0] = m00r * a0r - m00i * a0i + m01r * a1r - m01i * a1i;
        im[d0] = m00r * a0i + m00i * a0r + m01r * a1i + m01i * a1r;
        re[d1] = m10r * a0r - m10i * a0i + m11r * a1r - m11i * a1i;
        im[d1] = m10r * a0i + m10i * a0r + m11r * a1i + m11i * a1r;
      }
      __syncthreads();
    }
    int r = (l % 7) + 1;
    for (int wi = 0; wi < 8; ++wi) {
      int c = wi, tg = (wi + r) & 7;
      int pc = 7 - c, pt = 7 - tg;
      int p1 = pc > pt ? pc : pt, p0 = pc < pt ? pc : pt;
      if (t < 64) {
        int lm0 = (1 << p0) - 1;
        int v2 = ((t & ~lm0) << 1) | (t & lm0);
        int lm1 = (1 << p1) - 1;
        int db = ((v2 & ~lm1) << 1) | (v2 & lm1);
        int d0 = db | (1 << pc);
        int d1 = d0 | (1 << pt);
        float tr = re[d0], ti = im[d0];
        re[d0] = re[d1]; im[d0] = im[d1];
        re[d1] = tr;     im[d1] = ti;
      }
      __syncthreads();
    }
  }
  int pop = __popc(k) & 3;
  for (int idx = t; idx < 512; idx += 256) {
    int n = idx;
    int d = n & 255;
    float vr = re[d], vi = im[d];
    float pr, qi;
    if (pop == 0)      { pr =  vr; qi =  vi; }
    else if (pop == 1) { pr =  vi; qi = -vr; }
    else if (pop == 2) { pr = -vr; qi = -vi; }
    else               { pr = -vi; qi =  vr; }
    float val = (n < 256) ? pr : qi;
    int off = (((k >> 5) * 32 + (n >> 4)) * 64 + ((k >> 3) & 3) * 16 + (n & 15)) * 8 + (k & 7);
    wf16[off] = f2h_bits(val);
  }
}

// ---------------- Kernel 2: m-gen + fp16 GEMM + epilogue (M=64, 8 waves) ----
__global__ __launch_bounds__(512, 2) void quanv_main(
    const float* __restrict__ cs, const float* __restrict__ sn,
    const f16x8* __restrict__ wf, const float* __restrict__ bias,
    float* __restrict__ out) {
  __shared__ __align__(16) unsigned short R0[64 * 264];  // A-frag (32KB used) / probs [64][264]
  __shared__ float esm[512];
  const int tid = threadIdx.x;
  const int lane = tid & 63;
  const int wave = tid >> 6;
  const int pbase = blockIdx.x * 64;

  // --- phase 1: m-tile [64 x 256] fp16, FRAGMENT order, single pass ---
  // thread (s=tid>>8, q=(tid>>5)&7, pl=tid&31): patch pbase+s*32+pl, k-octant q.
  {
    int pl = tid & 31;
    int q = (tid >> 5) & 7;
    int s = tid >> 8;
    int patch = pbase + s * 32 + pl;
    if (patch > TOTAL_PATCHES - 1) patch = TOTAL_PATCHES - 1;
    int b = patch / LOUT;
    int l = patch - b * LOUT;
    int base = b * LBATCH + l;
    float fc[8], fs[8];
#pragma unroll
    for (int wq = 0; wq < 8; ++wq) { fc[wq] = cs[base + wq]; fs[wq] = sn[base + wq]; }
    // k = q*32 + idx5; k bits 7..5 = q (wires 0..2); idx5 bit lev = wire 7-lev
    float arr[32];
    arr[0] = ((q & 4) ? fs[0] : fc[0]) * ((q & 2) ? fs[1] : fc[1]) * ((q & 1) ? fs[2] : fc[2]);
#pragma unroll
    for (int lev = 0; lev < 5; ++lev) {
      int wq = 7 - lev;
      int sz = 1 << lev;
#pragma unroll
      for (int j = 0; j < 32; ++j) {
        if (j < sz) {
          float a = arr[j];
          arr[sz + j] = a * fs[wq];
          arr[j] = a * fc[wq];
        }
      }
    }
    int mtg = s * 2 + (pl >> 4);                    // global m-tile 0..3
    int fragbase = (q * 4 + mtg) * 64 + (pl & 15);
#pragma unroll
    for (int khalf = 0; khalf < 4; ++khalf) {
      f16x8 vH;
#pragma unroll
      for (int jj = 0; jj < 8; ++jj) vH[jj] = (_Float16)arr[khalf * 8 + jj];
      *(f16x8*)&R0[(fragbase + khalf * 16) * 8] = vH;
    }
  }
  __syncthreads();

  // --- phase 2: fp16 GEMM; wave owns nt {2w,2w+1} (Re) + {16+2w,16+2w+1} (Im),
  //     all 4 mt => acc[4][4] = 64 regs ---
  f32x4 acc[4][4];
#pragma unroll
  for (int i = 0; i < 4; ++i)
#pragma unroll
    for (int j = 0; j < 4; ++j) acc[i][j] = (f32x4){0.f, 0.f, 0.f, 0.f};

#pragma unroll
  for (int kc = 0; kc < 8; ++kc) {
    f16x8 af[4];
#pragma unroll
    for (int mt = 0; mt < 4; ++mt)
      af[mt] = *(const f16x8*)&R0[((kc * 4 + mt) * 64 + lane) * 8];
#pragma unroll
    for (int t4 = 0; t4 < 4; ++t4) {
      int nt = (t4 < 2) ? (wave * 2 + t4) : (16 + wave * 2 + (t4 - 2));
      f16x8 b = wf[(kc * 32 + nt) * 64 + lane];
#pragma unroll
      for (int mt = 0; mt < 4; ++mt)
        acc[mt][t4] = __builtin_amdgcn_mfma_f32_16x16x32_f16(af[mt], b, acc[mt][t4], 0, 0, 0);
    }
  }

  __syncthreads();
  // --- phase 3: probs p = re^2+im^2, single fp16 -> [64][264] (alias) ---
#pragma unroll
  for (int mt = 0; mt < 4; ++mt)
#pragma unroll
    for (int t2 = 0; t2 < 2; ++t2)
#pragma unroll
      for (int r = 0; r < 4; ++r) {
        float vr = acc[mt][t2][r], vi = acc[mt][t2 + 2][r];
        float p = vr * vr + vi * vi;
        int patch_l = mt * 16 + (lane >> 4) * 4 + r;
        int d = (wave * 2 + t2) * 16 + (lane & 15);
        R0[patch_l * 264 + d] = f2h_bits(p);
      }
  __syncthreads();

  // --- phase 4: sign-GEMM (waves 0..3, 16 patches each) ---
  if (wave < 4) {
    f32x4 e4 = {0.f, 0.f, 0.f, 0.f};
    int io = lane & 15;
    int plr = wave * 16 + (lane & 15);
    int hi4 = lane >> 4;
#pragma unroll
    for (int kc2 = 0; kc2 < 8; ++kc2) {
      int k0 = kc2 * 32 + hi4 * 8;
      f16x8 aH = *(const f16x8*)&R0[plr * 264 + k0];
      f16x8 b2;
#pragma unroll
      for (int bb = 0; bb < 8; ++bb) {
        _Float16 sv = (_Float16)0.f;
        if (io < 8) sv = (((k0 + bb) >> (7 - io)) & 1) ? (_Float16)(-1.f) : (_Float16)(1.f);
        b2[bb] = sv;
      }
      e4 = __builtin_amdgcn_mfma_f32_16x16x32_f16(aH, b2, e4, 0, 0, 0);
    }
    if (io < 8) {
      float bv = bias[io];
#pragma unroll
      for (int r = 0; r < 4; ++r)
        esm[io * 64 + (wave * 16 + hi4 * 4 + r)] = e4[r] + bv;
    }
  }
  __syncthreads();

  // --- phase 5: coalesced transposed store out[b][i][l], single pass ---
  {
    int io2 = tid >> 6, pl2 = tid & 63;
    int patch = pbase + pl2;
    if (patch < TOTAL_PATCHES) {
      int b = patch / LOUT;
      int l = patch - b * LOUT;
      out[(b * 8 + io2) * LOUT + l] = esm[io2 * 64 + pl2];
    }
  }
}

extern "C" void kernel_launch(void* const* d_in, const int* in_sizes, int n_in,
                              void* d_out, int out_size, void* d_ws, size_t ws_size,
                              hipStream_t stream) {
  const float* x = (const float*)d_in[0];
  const float* w = (const float*)d_in[1];
  const float* bias = (const float*)d_in[2];
  float* out = (float*)d_out;
  char* ws = (char*)d_ws;
  unsigned short* wf16 = (unsigned short*)ws;           // 262144 B
  float* cs = (float*)(ws + 262144);                    // 262144 B
  float* sn = (float*)(ws + 524288);                    // 262144 B

  prep_all<<<512, 256, 0, stream>>>(x, w, wf16, cs, sn);
  quanv_main<<<1024, 512, 0, stream>>>(cs, sn, (const f16x8*)wf16, bias, out);
}

// Round 13
// 38.146 us; speedup vs baseline: 1.6495x; 1.0234x over previous
//
#include <hip/hip_runtime.h>
#include <hip/hip_bf16.h>

// Quanv1D: out[i] = bias[i] + sum_d s_i(d) |(W' m_p)_d|^2
// R13 = R12 (fp16 single-term GEMM, frag-order A, acc<=64 regs/wave) with
// M-tile 64 -> 128 at 1024 threads / 16 waves:
//   wave owns 8 mt x {nt=wave (Re), nt=16+wave (Im)} => acc[8][2]=64 regs,
//   B traffic 4 KB -> 2 KB per patch (262 -> 134 MB L2 total).
//   LDS: A-frag 64KB / probs [128][264] fp16 (aliased) + esm 4KB = 70 KB.
// cs/sn now interleaved float2 (csn) -- halves phase-1 load instructions.
// launch_bounds(1024,1); NEVER tight VGPR caps ((256,4)-class) -- they
// silently miscompile acc-heavy MFMA kernels (R3/R4/R5 vs R7).

#define TOTAL_PATCHES 65480
#define LOUT 8185
#define LBATCH 8192

typedef _Float16 f16x8 __attribute__((ext_vector_type(8)));
typedef float f32x4 __attribute__((ext_vector_type(4)));

static __device__ __forceinline__ unsigned short f2h_bits(float f) {
  union { _Float16 h; unsigned short u; } v;
  v.h = (_Float16)f;
  return v.u;
}

// ---------------- Kernel 1: fused W'-build (blocks 0..255) + angle tables ----
// W' layout: flat_short_idx = ((kc*32 + nt)*64 + lane)*8 + j
// k = kc*32 + (lane>>4)*8 + j (K index), n = nt*16 + (lane&15) (col).
__global__ __launch_bounds__(256) void prep_all(const float* __restrict__ x,
                                                const float* __restrict__ w,
                                                unsigned short* __restrict__ wf16,
                                                float2* __restrict__ csn) {
  if (blockIdx.x >= 256) {
    int e = (blockIdx.x - 256) * 256 + threadIdx.x;
    float t = tanhf(x[e]);
    float s, c;
    __sincosf(1.57079632679489662f * t, &s, &c);
    csn[e] = make_float2(c, s);
    return;
  }
  __shared__ float re[256], im[256];
  const int k = blockIdx.x;
  const int t = threadIdx.x;
  re[t] = 0.f; im[t] = 0.f;
  __syncthreads();
  if (t == 0) re[k] = 1.f;
  __syncthreads();
  for (int l = 0; l < 2; ++l) {
    for (int wi = 0; wi < 8; ++wi) {
      float phi = w[(l * 8 + wi) * 3 + 0];
      float th  = w[(l * 8 + wi) * 3 + 1];
      float om  = w[(l * 8 + wi) * 3 + 2];
      float ch = cosf(0.5f * th), sh = sinf(0.5f * th);
      float aa = 0.5f * (phi + om), bb = 0.5f * (phi - om);
      float ca = cosf(aa), sa = sinf(aa), cb = cosf(bb), sb = sinf(bb);
      float m00r = ch * ca, m00i = -ch * sa;
      float m01r = -sh * cb, m01i = -sh * sb;
      float m10r = sh * cb,  m10i = -sh * sb;
      float m11r = ch * ca,  m11i = ch * sa;
      int pos = 7 - wi;
      int mask = 1 << pos;
      int lowm = mask - 1;
      if (t < 128) {
        int pp = t;
        int d0 = ((pp & ~lowm) << 1) | (pp & lowm);
        int d1 = d0 | mask;
        float a0r = re[d0], a0i = im[d0], a1r = re[d1], a1i = im[d1];
        re[d0] = m00r * a0r - m00i * a0i + m01r * a1r - m01i * a1i;
        im[d0] = m00r * a0i + m00i * a0r + m01r * a1i + m01i * a1r;
        re[d1] = m10r * a0r - m10i * a0i + m11r * a1r - m11i * a1i;
        im[d1] = m10r * a0i + m10i * a0r + m11r * a1i + m11i * a1r;
      }
      __syncthreads();
    }
    int r = (l % 7) + 1;
    for (int wi = 0; wi < 8; ++wi) {
      int c = wi, tg = (wi + r) & 7;
      int pc = 7 - c, pt = 7 - tg;
      int p1 = pc > pt ? pc : pt, p0 = pc < pt ? pc : pt;
      if (t < 64) {
        int lm0 = (1 << p0) - 1;
        int v2 = ((t & ~lm0) << 1) | (t & lm0);
        int lm1 = (1 << p1) - 1;
        int db = ((v2 & ~lm1) << 1) | (v2 & lm1);
        int d0 = db | (1 << pc);
        int d1 = d0 | (1 << pt);
        float tr = re[d0], ti = im[d0];
        re[d0] = re[d1]; im[d0] = im[d1];
        re[d1] = tr;     im[d1] = ti;
      }
      __syncthreads();
    }
  }
  int pop = __popc(k) & 3;
  for (int idx = t; idx < 512; idx += 256) {
    int n = idx;
    int d = n & 255;
    float vr = re[d], vi = im[d];
    float pr, qi;
    if (pop == 0)      { pr =  vr; qi =  vi; }
    else if (pop == 1) { pr =  vi; qi = -vr; }
    else if (pop == 2) { pr = -vr; qi = -vi; }
    else               { pr = -vi; qi =  vr; }
    float val = (n < 256) ? pr : qi;
    int off = (((k >> 5) * 32 + (n >> 4)) * 64 + ((k >> 3) & 3) * 16 + (n & 15)) * 8 + (k & 7);
    wf16[off] = f2h_bits(val);
  }
}

// ---------------- Kernel 2: m-gen + fp16 GEMM + epilogue (M=128, 16 waves) ----
__global__ __launch_bounds__(1024, 1) void quanv_main(
    const float2* __restrict__ csn,
    const f16x8* __restrict__ wf, const float* __restrict__ bias,
    float* __restrict__ out) {
  __shared__ __align__(16) unsigned short R0[128 * 264];  // A-frag (64KB used) / probs [128][264]
  __shared__ float esm[1024];
  const int tid = threadIdx.x;
  const int lane = tid & 63;
  const int wave = tid >> 6;
  const int pbase = blockIdx.x * 128;

  // --- phase 1: m-tile [128 x 256] fp16, FRAGMENT order, single pass ---
  // thread (s=tid>>8 in 0..3, q=(tid>>5)&7, pl=tid&31): patch pbase+s*32+pl,
  // k-octant q. Global m-tile mtg = s*2 + (pl>>4) in 0..7.
  {
    int pl = tid & 31;
    int q = (tid >> 5) & 7;
    int s = tid >> 8;
    int patch = pbase + s * 32 + pl;
    if (patch > TOTAL_PATCHES - 1) patch = TOTAL_PATCHES - 1;
    int b = patch / LOUT;
    int l = patch - b * LOUT;
    int base = b * LBATCH + l;
    float fc[8], fs[8];
#pragma unroll
    for (int wq = 0; wq < 8; ++wq) {
      float2 v = csn[base + wq];
      fc[wq] = v.x; fs[wq] = v.y;
    }
    // k = q*32 + idx5; k bits 7..5 = q (wires 0..2); idx5 bit lev = wire 7-lev
    float arr[32];
    arr[0] = ((q & 4) ? fs[0] : fc[0]) * ((q & 2) ? fs[1] : fc[1]) * ((q & 1) ? fs[2] : fc[2]);
#pragma unroll
    for (int lev = 0; lev < 5; ++lev) {
      int wq = 7 - lev;
      int sz = 1 << lev;
#pragma unroll
      for (int j = 0; j < 32; ++j) {
        if (j < sz) {
          float a = arr[j];
          arr[sz + j] = a * fs[wq];
          arr[j] = a * fc[wq];
        }
      }
    }
    int mtg = s * 2 + (pl >> 4);                    // 0..7
    int fragbase = (q * 8 + mtg) * 64 + (pl & 15);
#pragma unroll
    for (int khalf = 0; khalf < 4; ++khalf) {
      f16x8 vH;
#pragma unroll
      for (int jj = 0; jj < 8; ++jj) vH[jj] = (_Float16)arr[khalf * 8 + jj];
      *(f16x8*)&R0[(fragbase + khalf * 16) * 8] = vH;
    }
  }
  __syncthreads();

  // --- phase 2: fp16 GEMM; wave owns nt=wave (Re) + nt=16+wave (Im),
  //     all 8 mt => acc[8][2] = 64 regs ---
  f32x4 acc[8][2];
#pragma unroll
  for (int i = 0; i < 8; ++i)
#pragma unroll
    for (int j = 0; j < 2; ++j) acc[i][j] = (f32x4){0.f, 0.f, 0.f, 0.f};

#pragma unroll
  for (int kc = 0; kc < 8; ++kc) {
    f16x8 af[8];
#pragma unroll
    for (int mt = 0; mt < 8; ++mt)
      af[mt] = *(const f16x8*)&R0[((kc * 8 + mt) * 64 + lane) * 8];
#pragma unroll
    for (int t2 = 0; t2 < 2; ++t2) {
      int nt = (t2 == 0) ? wave : (16 + wave);
      f16x8 b = wf[(kc * 32 + nt) * 64 + lane];
#pragma unroll
      for (int mt = 0; mt < 8; ++mt)
        acc[mt][t2] = __builtin_amdgcn_mfma_f32_16x16x32_f16(af[mt], b, acc[mt][t2], 0, 0, 0);
    }
  }

  __syncthreads();
  // --- phase 3: probs p = re^2+im^2, single fp16 -> [128][264] (alias) ---
#pragma unroll
  for (int mt = 0; mt < 8; ++mt)
#pragma unroll
    for (int r = 0; r < 4; ++r) {
      float vr = acc[mt][0][r], vi = acc[mt][1][r];
      float p = vr * vr + vi * vi;
      int patch_l = mt * 16 + (lane >> 4) * 4 + r;
      int d = wave * 16 + (lane & 15);
      R0[patch_l * 264 + d] = f2h_bits(p);
    }
  __syncthreads();

  // --- phase 4: sign-GEMM (waves 0..7, 16 patches each) ---
  if (wave < 8) {
    f32x4 e4 = {0.f, 0.f, 0.f, 0.f};
    int io = lane & 15;
    int plr = wave * 16 + (lane & 15);
    int hi4 = lane >> 4;
#pragma unroll
    for (int kc2 = 0; kc2 < 8; ++kc2) {
      int k0 = kc2 * 32 + hi4 * 8;
      f16x8 aH = *(const f16x8*)&R0[plr * 264 + k0];
      f16x8 b2;
#pragma unroll
      for (int bb = 0; bb < 8; ++bb) {
        _Float16 sv = (_Float16)0.f;
        if (io < 8) sv = (((k0 + bb) >> (7 - io)) & 1) ? (_Float16)(-1.f) : (_Float16)(1.f);
        b2[bb] = sv;
      }
      e4 = __builtin_amdgcn_mfma_f32_16x16x32_f16(aH, b2, e4, 0, 0, 0);
    }
    if (io < 8) {
      float bv = bias[io];
#pragma unroll
      for (int r = 0; r < 4; ++r)
        esm[io * 128 + (wave * 16 + hi4 * 4 + r)] = e4[r] + bv;
    }
  }
  __syncthreads();

  // --- phase 5: coalesced transposed store out[b][i][l], single pass ---
  {
    int io2 = tid >> 7, pl2 = tid & 127;
    int patch = pbase + pl2;
    if (patch < TOTAL_PATCHES) {
      int b = patch / LOUT;
      int l = patch - b * LOUT;
      out[(b * 8 + io2) * LOUT + l] = esm[io2 * 128 + pl2];
    }
  }
}

extern "C" void kernel_launch(void* const* d_in, const int* in_sizes, int n_in,
                              void* d_out, int out_size, void* d_ws, size_t ws_size,
                              hipStream_t stream) {
  const float* x = (const float*)d_in[0];
  const float* w = (const float*)d_in[1];
  const float* bias = (const float*)d_in[2];
  float* out = (float*)d_out;
  char* ws = (char*)d_ws;
  unsigned short* wf16 = (unsigned short*)ws;           // 262144 B
  float2* csn = (float2*)(ws + 262144);                 // 524288 B

  prep_all<<<512, 256, 0, stream>>>(x, w, wf16, csn);
  quanv_main<<<512, 1024, 0, stream>>>(csn, (const f16x8*)wf16, bias, out);
}

// Round 14
// 37.355 us; speedup vs baseline: 1.6844x; 1.0212x over previous
//
#include <hip/hip_runtime.h>
#include <hip/hip_bf16.h>

// Quanv1D: out[i] = bias[i] + sum_d s_i(d) |(W' m_p)_d|^2
// R14 = R13 (fp16 single-term GEMM, M=128/16-wave, frag-order A, acc 64
// regs/wave) with angle tables fused into quanv_main:
//   per-block 144-entry LDS cos/sin window (x-window is contiguous, <=142
//   elements even across a batch boundary: off = base - base0 in [0,141]),
//   prep_all trimmed to 256 unitary-only blocks, csn buffer deleted.
// Register budget note: 1024-thr block => 16 waves => <=128 unified
// regs/wave hard cap; acc 64 + ~60 arch sits at the edge -- do NOT add
// register prefetch here. NEVER tight VGPR caps ((256,4)-class) -- silent
// miscompile (R3/R4/R5 vs R7).

#define TOTAL_PATCHES 65480
#define LOUT 8185
#define LBATCH 8192
#define NX 65536

typedef _Float16 f16x8 __attribute__((ext_vector_type(8)));
typedef float f32x4 __attribute__((ext_vector_type(4)));

static __device__ __forceinline__ unsigned short f2h_bits(float f) {
  union { _Float16 h; unsigned short u; } v;
  v.h = (_Float16)f;
  return v.u;
}

// ---------------- Kernel 1: W'-build (256 blocks) ------------------------
// W' layout: flat_short_idx = ((kc*32 + nt)*64 + lane)*8 + j
// k = kc*32 + (lane>>4)*8 + j (K index), n = nt*16 + (lane&15) (col).
__global__ __launch_bounds__(256) void prep_all(const float* __restrict__ w,
                                                unsigned short* __restrict__ wf16) {
  __shared__ float re[256], im[256];
  const int k = blockIdx.x;
  const int t = threadIdx.x;
  re[t] = 0.f; im[t] = 0.f;
  __syncthreads();
  if (t == 0) re[k] = 1.f;
  __syncthreads();
  for (int l = 0; l < 2; ++l) {
    for (int wi = 0; wi < 8; ++wi) {
      float phi = w[(l * 8 + wi) * 3 + 0];
      float th  = w[(l * 8 + wi) * 3 + 1];
      float om  = w[(l * 8 + wi) * 3 + 2];
      float ch = cosf(0.5f * th), sh = sinf(0.5f * th);
      float aa = 0.5f * (phi + om), bb = 0.5f * (phi - om);
      float ca = cosf(aa), sa = sinf(aa), cb = cosf(bb), sb = sinf(bb);
      float m00r = ch * ca, m00i = -ch * sa;
      float m01r = -sh * cb, m01i = -sh * sb;
      float m10r = sh * cb,  m10i = -sh * sb;
      float m11r = ch * ca,  m11i = ch * sa;
      int pos = 7 - wi;
      int mask = 1 << pos;
      int lowm = mask - 1;
      if (t < 128) {
        int pp = t;
        int d0 = ((pp & ~lowm) << 1) | (pp & lowm);
        int d1 = d0 | mask;
        float a0r = re[d0], a0i = im[d0], a1r = re[d1], a1i = im[d1];
        re[d0] = m00r * a0r - m00i * a0i + m01r * a1r - m01i * a1i;
        im[d0] = m00r * a0i + m00i * a0r + m01r * a1i + m01i * a1r;
        re[d1] = m10r * a0r - m10i * a0i + m11r * a1r - m11i * a1i;
        im[d1] = m10r * a0i + m10i * a0r + m11r * a1i + m11i * a1r;
      }
      __syncthreads();
    }
    int r = (l % 7) + 1;
    for (int wi = 0; wi < 8; ++wi) {
      int c = wi, tg = (wi + r) & 7;
      int pc = 7 - c, pt = 7 - tg;
      int p1 = pc > pt ? pc : pt, p0 = pc < pt ? pc : pt;
      if (t < 64) {
        int lm0 = (1 << p0) - 1;
        int v2 = ((t & ~lm0) << 1) | (t & lm0);
        int lm1 = (1 << p1) - 1;
        int db = ((v2 & ~lm1) << 1) | (v2 & lm1);
        int d0 = db | (1 << pc);
        int d1 = d0 | (1 << pt);
        float tr = re[d0], ti = im[d0];
        re[d0] = re[d1]; im[d0] = im[d1];
        re[d1] = tr;     im[d1] = ti;
      }
      __syncthreads();
    }
  }
  int pop = __popc(k) & 3;
  for (int idx = t; idx < 512; idx += 256) {
    int n = idx;
    int d = n & 255;
    float vr = re[d], vi = im[d];
    float pr, qi;
    if (pop == 0)      { pr =  vr; qi =  vi; }
    else if (pop == 1) { pr =  vi; qi = -vr; }
    else if (pop == 2) { pr = -vr; qi = -vi; }
    else               { pr = -vi; qi =  vr; }
    float val = (n < 256) ? pr : qi;
    int off = (((k >> 5) * 32 + (n >> 4)) * 64 + ((k >> 3) & 3) * 16 + (n & 15)) * 8 + (k & 7);
    wf16[off] = f2h_bits(val);
  }
}

// ---------------- Kernel 2: angles + m-gen + fp16 GEMM + epilogue --------
__global__ __launch_bounds__(1024, 1) void quanv_main(
    const float* __restrict__ x,
    const f16x8* __restrict__ wf, const float* __restrict__ bias,
    float* __restrict__ out) {
  __shared__ __align__(16) unsigned short R0[128 * 264];  // A-frag (64KB used) / probs [128][264]
  __shared__ float esm[1024];
  __shared__ float2 cssn2[144];
  const int tid = threadIdx.x;
  const int lane = tid & 63;
  const int wave = tid >> 6;
  const int pbase = blockIdx.x * 128;

  // --- phase 0: per-block cos/sin window (<=142 contiguous x elements) ---
  const int b0 = pbase / LOUT;
  const int base0 = b0 * LBATCH + (pbase - b0 * LOUT);
  if (tid < 144) {
    int g = base0 + tid;
    if (g > NX - 1) g = NX - 1;
    float t = tanhf(x[g]);
    float s, c;
    __sincosf(1.57079632679489662f * t, &s, &c);
    cssn2[tid] = make_float2(c, s);
  }
  __syncthreads();

  // --- phase 1: m-tile [128 x 256] fp16, FRAGMENT order, single pass ---
  // thread (s=tid>>8 in 0..3, q=(tid>>5)&7, pl=tid&31): patch pbase+s*32+pl.
  {
    int pl = tid & 31;
    int q = (tid >> 5) & 7;
    int s = tid >> 8;
    int patch = pbase + s * 32 + pl;
    if (patch > TOTAL_PATCHES - 1) patch = TOTAL_PATCHES - 1;
    int b = patch / LOUT;
    int off0 = b * LBATCH + (patch - b * LOUT) - base0;   // 0..141
    float fc[8], fs[8];
#pragma unroll
    for (int wq = 0; wq < 8; ++wq) {
      float2 v = cssn2[off0 + wq];
      fc[wq] = v.x; fs[wq] = v.y;
    }
    // k = q*32 + idx5; k bits 7..5 = q (wires 0..2); idx5 bit lev = wire 7-lev
    float arr[32];
    arr[0] = ((q & 4) ? fs[0] : fc[0]) * ((q & 2) ? fs[1] : fc[1]) * ((q & 1) ? fs[2] : fc[2]);
#pragma unroll
    for (int lev = 0; lev < 5; ++lev) {
      int wq = 7 - lev;
      int sz = 1 << lev;
#pragma unroll
      for (int j = 0; j < 32; ++j) {
        if (j < sz) {
          float a = arr[j];
          arr[sz + j] = a * fs[wq];
          arr[j] = a * fc[wq];
        }
      }
    }
    int mtg = s * 2 + (pl >> 4);                    // 0..7
    int fragbase = (q * 8 + mtg) * 64 + (pl & 15);
#pragma unroll
    for (int khalf = 0; khalf < 4; ++khalf) {
      f16x8 vH;
#pragma unroll
      for (int jj = 0; jj < 8; ++jj) vH[jj] = (_Float16)arr[khalf * 8 + jj];
      *(f16x8*)&R0[(fragbase + khalf * 16) * 8] = vH;
    }
  }
  __syncthreads();

  // --- phase 2: fp16 GEMM; wave owns nt=wave (Re) + nt=16+wave (Im),
  //     all 8 mt => acc[8][2] = 64 regs ---
  f32x4 acc[8][2];
#pragma unroll
  for (int i = 0; i < 8; ++i)
#pragma unroll
    for (int j = 0; j < 2; ++j) acc[i][j] = (f32x4){0.f, 0.f, 0.f, 0.f};

#pragma unroll
  for (int kc = 0; kc < 8; ++kc) {
    f16x8 af[8];
#pragma unroll
    for (int mt = 0; mt < 8; ++mt)
      af[mt] = *(const f16x8*)&R0[((kc * 8 + mt) * 64 + lane) * 8];
#pragma unroll
    for (int t2 = 0; t2 < 2; ++t2) {
      int nt = (t2 == 0) ? wave : (16 + wave);
      f16x8 b = wf[(kc * 32 + nt) * 64 + lane];
#pragma unroll
      for (int mt = 0; mt < 8; ++mt)
        acc[mt][t2] = __builtin_amdgcn_mfma_f32_16x16x32_f16(af[mt], b, acc[mt][t2], 0, 0, 0);
    }
  }

  __syncthreads();
  // --- phase 3: probs p = re^2+im^2, single fp16 -> [128][264] (alias) ---
#pragma unroll
  for (int mt = 0; mt < 8; ++mt)
#pragma unroll
    for (int r = 0; r < 4; ++r) {
      float vr = acc[mt][0][r], vi = acc[mt][1][r];
      float p = vr * vr + vi * vi;
      int patch_l = mt * 16 + (lane >> 4) * 4 + r;
      int d = wave * 16 + (lane & 15);
      R0[patch_l * 264 + d] = f2h_bits(p);
    }
  __syncthreads();

  // --- phase 4: sign-GEMM (waves 0..7, 16 patches each) ---
  if (wave < 8) {
    f32x4 e4 = {0.f, 0.f, 0.f, 0.f};
    int io = lane & 15;
    int plr = wave * 16 + (lane & 15);
    int hi4 = lane >> 4;
#pragma unroll
    for (int kc2 = 0; kc2 < 8; ++kc2) {
      int k0 = kc2 * 32 + hi4 * 8;
      f16x8 aH = *(const f16x8*)&R0[plr * 264 + k0];
      f16x8 b2;
#pragma unroll
      for (int bb = 0; bb < 8; ++bb) {
        _Float16 sv = (_Float16)0.f;
        if (io < 8) sv = (((k0 + bb) >> (7 - io)) & 1) ? (_Float16)(-1.f) : (_Float16)(1.f);
        b2[bb] = sv;
      }
      e4 = __builtin_amdgcn_mfma_f32_16x16x32_f16(aH, b2, e4, 0, 0, 0);
    }
    if (io < 8) {
      float bv = bias[io];
#pragma unroll
      for (int r = 0; r < 4; ++r)
        esm[io * 128 + (wave * 16 + hi4 * 4 + r)] = e4[r] + bv;
    }
  }
  __syncthreads();

  // --- phase 5: coalesced transposed store out[b][i][l], single pass ---
  {
    int io2 = tid >> 7, pl2 = tid & 127;
    int patch = pbase + pl2;
    if (patch < TOTAL_PATCHES) {
      int b = patch / LOUT;
      int l = patch - b * LOUT;
      out[(b * 8 + io2) * LOUT + l] = esm[io2 * 128 + pl2];
    }
  }
}

extern "C" void kernel_launch(void* const* d_in, const int* in_sizes, int n_in,
                              void* d_out, int out_size, void* d_ws, size_t ws_size,
                              hipStream_t stream) {
  const float* x = (const float*)d_in[0];
  const float* w = (const float*)d_in[1];
  const float* bias = (const float*)d_in[2];
  float* out = (float*)d_out;
  char* ws = (char*)d_ws;
  unsigned short* wf16 = (unsigned short*)ws;           // 262144 B

  prep_all<<<256, 256, 0, stream>>>(w, wf16);
  quanv_main<<<512, 1024, 0, stream>>>(x, (const f16x8*)wf16, bias, out);
}

// Round 15
// 36.543 us; speedup vs baseline: 1.7219x; 1.0222x over previous
//
#include <hip/hip_runtime.h>
#include <hip/hip_bf16.h>

// Quanv1D: out[i] = bias[i] + sum_d s_i(d) |(W' m_p)_d|^2
// R15 = R14 (fp16 single-term GEMM, M=128/16-wave, frag-order A, fused
// angle window; quanv_main byte-identical) with prep_all rewritten as a
// wave-synchronous in-register circuit simulator:
//   1 wave per basis state k; state = 4 complex/lane in regs;
//   Rot gates: shfl_xor butterflies (pos>=2) or slot butterflies (pos<2);
//   CNOTs: shfl with computed src lane / slot select. No LDS, no barriers
//   (was 32 __syncthreads). Loops fully unrolled => pc/pt compile-time,
//   no dynamic register indexing.
// Register budget: 1024-thr main block => <=128 unified regs/wave; acc 64
// + ~60 arch at the edge -- no reg prefetch. NEVER tight VGPR caps
// ((256,4)-class) -- silent miscompile (R3/R4/R5 vs R7).

#define TOTAL_PATCHES 65480
#define LOUT 8185
#define LBATCH 8192
#define NX 65536

typedef _Float16 f16x8 __attribute__((ext_vector_type(8)));
typedef float f32x4 __attribute__((ext_vector_type(4)));

static __device__ __forceinline__ unsigned short f2h_bits(float f) {
  union { _Float16 h; unsigned short u; } v;
  v.h = (_Float16)f;
  return v.u;
}

// ---------------- Kernel 1: W'-build, wave-register version --------------
// Block k (256 blocks x 64 threads): evolve |k> through 2x(8 Rot + 8 CNOT).
// Lane holds state amps for d = lane*4 + s, s=0..3.
// Output layout unchanged: off = (((k>>5)*32 + (n>>4))*64 + ((k>>3)&3)*16
//                                 + (n&15))*8 + (k&7);  n<256:Re, n>=256:Im.
__global__ __launch_bounds__(64) void prep_all(const float* __restrict__ w,
                                               unsigned short* __restrict__ wf16) {
  const int k = blockIdx.x;
  const int lane = threadIdx.x;
  float re[4], im[4];
#pragma unroll
  for (int s = 0; s < 4; ++s) {
    re[s] = (lane * 4 + s == k) ? 1.f : 0.f;
    im[s] = 0.f;
  }

#pragma unroll
  for (int l = 0; l < 2; ++l) {
    // ---- 8 Rot gates ----
#pragma unroll
    for (int wi = 0; wi < 8; ++wi) {
      float phi = w[(l * 8 + wi) * 3 + 0];
      float th  = w[(l * 8 + wi) * 3 + 1];
      float om  = w[(l * 8 + wi) * 3 + 2];
      float ch = cosf(0.5f * th), sh = sinf(0.5f * th);
      float aa = 0.5f * (phi + om), bb = 0.5f * (phi - om);
      float ca = cosf(aa), sa = sinf(aa), cb = cosf(bb), sb = sinf(bb);
      float m00r = ch * ca, m00i = -ch * sa;
      float m01r = -sh * cb, m01i = -sh * sb;
      float m10r = sh * cb,  m10i = -sh * sb;
      float m11r = ch * ca,  m11i = ch * sa;
      const int p = 7 - wi;
      float or_[4], oi_[4];
#pragma unroll
      for (int s = 0; s < 4; ++s) { or_[s] = re[s]; oi_[s] = im[s]; }
#pragma unroll
      for (int s = 0; s < 4; ++s) {
        float pr_, pi_;
        if (p >= 2) {
          pr_ = __shfl_xor(or_[s], 1 << (p - 2), 64);
          pi_ = __shfl_xor(oi_[s], 1 << (p - 2), 64);
        } else {
          pr_ = or_[s ^ (1 << p)];
          pi_ = oi_[s ^ (1 << p)];
        }
        int bit = ((lane * 4 + s) >> p) & 1;
        float cAr = bit ? m11r : m00r, cAi = bit ? m11i : m00i;
        float cBr = bit ? m10r : m01r, cBi = bit ? m10i : m01i;
        re[s] = cAr * or_[s] - cAi * oi_[s] + cBr * pr_ - cBi * pi_;
        im[s] = cAr * oi_[s] + cAi * or_[s] + cBr * pi_ + cBi * pr_;
      }
    }
    // ---- 8 CNOTs: control c=wi, target t=(wi+r)&7, r=l+1 ----
    const int r = l + 1;
#pragma unroll
    for (int wi = 0; wi < 8; ++wi) {
      const int pc = 7 - wi;
      const int pt = 7 - ((wi + r) & 7);
      float or_[4], oi_[4];
#pragma unroll
      for (int s = 0; s < 4; ++s) { or_[s] = re[s]; oi_[s] = im[s]; }
#pragma unroll
      for (int s = 0; s < 4; ++s) {
        int d = lane * 4 + s;
        int ctrl = (d >> pc) & 1;
        if (pt >= 2) {
          int srcl = lane ^ (ctrl << (pt - 2));
          re[s] = __shfl(or_[s], srcl, 64);
          im[s] = __shfl(oi_[s], srcl, 64);
        } else {
          float fr = or_[s ^ (1 << pt)], fi = oi_[s ^ (1 << pt)];
          re[s] = ctrl ? fr : or_[s];
          im[s] = ctrl ? fi : oi_[s];
        }
      }
    }
  }

  // ---- phase (-i)^popc(k) + store ----
  const int pop = __popc(k) & 3;
#pragma unroll
  for (int s = 0; s < 4; ++s) {
    int d = lane * 4 + s;
    float vr = re[s], vi = im[s];
    float pr, qi;
    if (pop == 0)      { pr =  vr; qi =  vi; }
    else if (pop == 1) { pr =  vi; qi = -vr; }
    else if (pop == 2) { pr = -vr; qi = -vi; }
    else               { pr = -vi; qi =  vr; }
    int offR = (((k >> 5) * 32 + (d >> 4)) * 64 + ((k >> 3) & 3) * 16 + (d & 15)) * 8 + (k & 7);
    int n2 = d + 256;
    int offI = (((k >> 5) * 32 + (n2 >> 4)) * 64 + ((k >> 3) & 3) * 16 + (n2 & 15)) * 8 + (k & 7);
    wf16[offR] = f2h_bits(pr);
    wf16[offI] = f2h_bits(qi);
  }
}

// ---------------- Kernel 2: angles + m-gen + fp16 GEMM + epilogue --------
__global__ __launch_bounds__(1024, 1) void quanv_main(
    const float* __restrict__ x,
    const f16x8* __restrict__ wf, const float* __restrict__ bias,
    float* __restrict__ out) {
  __shared__ __align__(16) unsigned short R0[128 * 264];  // A-frag (64KB used) / probs [128][264]
  __shared__ float esm[1024];
  __shared__ float2 cssn2[144];
  const int tid = threadIdx.x;
  const int lane = tid & 63;
  const int wave = tid >> 6;
  const int pbase = blockIdx.x * 128;

  // --- phase 0: per-block cos/sin window (<=142 contiguous x elements) ---
  const int b0 = pbase / LOUT;
  const int base0 = b0 * LBATCH + (pbase - b0 * LOUT);
  if (tid < 144) {
    int g = base0 + tid;
    if (g > NX - 1) g = NX - 1;
    float t = tanhf(x[g]);
    float s, c;
    __sincosf(1.57079632679489662f * t, &s, &c);
    cssn2[tid] = make_float2(c, s);
  }
  __syncthreads();

  // --- phase 1: m-tile [128 x 256] fp16, FRAGMENT order, single pass ---
  {
    int pl = tid & 31;
    int q = (tid >> 5) & 7;
    int s = tid >> 8;
    int patch = pbase + s * 32 + pl;
    if (patch > TOTAL_PATCHES - 1) patch = TOTAL_PATCHES - 1;
    int b = patch / LOUT;
    int off0 = b * LBATCH + (patch - b * LOUT) - base0;   // 0..141
    float fc[8], fs[8];
#pragma unroll
    for (int wq = 0; wq < 8; ++wq) {
      float2 v = cssn2[off0 + wq];
      fc[wq] = v.x; fs[wq] = v.y;
    }
    float arr[32];
    arr[0] = ((q & 4) ? fs[0] : fc[0]) * ((q & 2) ? fs[1] : fc[1]) * ((q & 1) ? fs[2] : fc[2]);
#pragma unroll
    for (int lev = 0; lev < 5; ++lev) {
      int wq = 7 - lev;
      int sz = 1 << lev;
#pragma unroll
      for (int j = 0; j < 32; ++j) {
        if (j < sz) {
          float a = arr[j];
          arr[sz + j] = a * fs[wq];
          arr[j] = a * fc[wq];
        }
      }
    }
    int mtg = s * 2 + (pl >> 4);                    // 0..7
    int fragbase = (q * 8 + mtg) * 64 + (pl & 15);
#pragma unroll
    for (int khalf = 0; khalf < 4; ++khalf) {
      f16x8 vH;
#pragma unroll
      for (int jj = 0; jj < 8; ++jj) vH[jj] = (_Float16)arr[khalf * 8 + jj];
      *(f16x8*)&R0[(fragbase + khalf * 16) * 8] = vH;
    }
  }
  __syncthreads();

  // --- phase 2: fp16 GEMM; wave owns nt=wave (Re) + nt=16+wave (Im) ---
  f32x4 acc[8][2];
#pragma unroll
  for (int i = 0; i < 8; ++i)
#pragma unroll
    for (int j = 0; j < 2; ++j) acc[i][j] = (f32x4){0.f, 0.f, 0.f, 0.f};

#pragma unroll
  for (int kc = 0; kc < 8; ++kc) {
    f16x8 af[8];
#pragma unroll
    for (int mt = 0; mt < 8; ++mt)
      af[mt] = *(const f16x8*)&R0[((kc * 8 + mt) * 64 + lane) * 8];
#pragma unroll
    for (int t2 = 0; t2 < 2; ++t2) {
      int nt = (t2 == 0) ? wave : (16 + wave);
      f16x8 b = wf[(kc * 32 + nt) * 64 + lane];
#pragma unroll
      for (int mt = 0; mt < 8; ++mt)
        acc[mt][t2] = __builtin_amdgcn_mfma_f32_16x16x32_f16(af[mt], b, acc[mt][t2], 0, 0, 0);
    }
  }

  __syncthreads();
  // --- phase 3: probs p = re^2+im^2, single fp16 -> [128][264] (alias) ---
#pragma unroll
  for (int mt = 0; mt < 8; ++mt)
#pragma unroll
    for (int r = 0; r < 4; ++r) {
      float vr = acc[mt][0][r], vi = acc[mt][1][r];
      float p = vr * vr + vi * vi;
      int patch_l = mt * 16 + (lane >> 4) * 4 + r;
      int d = wave * 16 + (lane & 15);
      R0[patch_l * 264 + d] = f2h_bits(p);
    }
  __syncthreads();

  // --- phase 4: sign-GEMM (waves 0..7, 16 patches each) ---
  if (wave < 8) {
    f32x4 e4 = {0.f, 0.f, 0.f, 0.f};
    int io = lane & 15;
    int plr = wave * 16 + (lane & 15);
    int hi4 = lane >> 4;
#pragma unroll
    for (int kc2 = 0; kc2 < 8; ++kc2) {
      int k0 = kc2 * 32 + hi4 * 8;
      f16x8 aH = *(const f16x8*)&R0[plr * 264 + k0];
      f16x8 b2;
#pragma unroll
      for (int bb = 0; bb < 8; ++bb) {
        _Float16 sv = (_Float16)0.f;
        if (io < 8) sv = (((k0 + bb) >> (7 - io)) & 1) ? (_Float16)(-1.f) : (_Float16)(1.f);
        b2[bb] = sv;
      }
      e4 = __builtin_amdgcn_mfma_f32_16x16x32_f16(aH, b2, e4, 0, 0, 0);
    }
    if (io < 8) {
      float bv = bias[io];
#pragma unroll
      for (int r = 0; r < 4; ++r)
        esm[io * 128 + (wave * 16 + hi4 * 4 + r)] = e4[r] + bv;
    }
  }
  __syncthreads();

  // --- phase 5: coalesced transposed store out[b][i][l], single pass ---
  {
    int io2 = tid >> 7, pl2 = tid & 127;
    int patch = pbase + pl2;
    if (patch < TOTAL_PATCHES) {
      int b = patch / LOUT;
      int l = patch - b * LOUT;
      out[(b * 8 + io2) * LOUT + l] = esm[io2 * 128 + pl2];
    }
  }
}

extern "C" void kernel_launch(void* const* d_in, const int* in_sizes, int n_in,
                              void* d_out, int out_size, void* d_ws, size_t ws_size,
                              hipStream_t stream) {
  const float* x = (const float*)d_in[0];
  const float* w = (const float*)d_in[1];
  const float* bias = (const float*)d_in[2];
  float* out = (float*)d_out;
  char* ws = (char*)d_ws;
  unsigned short* wf16 = (unsigned short*)ws;           // 262144 B

  prep_all<<<256, 64, 0, stream>>>(w, wf16);
  quanv_main<<<512, 1024, 0, stream>>>(x, (const f16x8*)wf16, bias, out);
}